// Round 1
// baseline (117.541 us; speedup 1.0000x reference)
//
#include <hip/hip_runtime.h>
#include <hip/hip_bf16.h>

// SelfContrastiveLoss: loss over E = exp(qn @ kn^T / T), B=8192, D=256.
// Only rowsum(E), colsum(E), diag-ish d_i are needed -> fused GEMM+exp+reduce.
//
// ws layout:
//   [0,            4 MB)  qn bf16   (8192*256*2)
//   [4 MB,         8 MB)  kn bf16
//   [8 MB,       +32 KB)  diag  d_i = exp(dot(qn_i,kn_i)/T)  fp32
//   [.. +32 KB]           rowsum fp32
//   [.. +32 KB]           colsum fp32
// total ~8.1 MB required of ws_size.

#define NB 8192
#define ND 256

constexpr float TEMP_INV = 20.0f;   // 1 / 0.05
constexpr float EPS = 1e-5f;

typedef float f32x4 __attribute__((ext_vector_type(4)));
typedef short s16x8 __attribute__((ext_vector_type(8)));

// ---------------- kernel 1: row L2-normalize -> bf16, plus fp32 diag ---------
__global__ __launch_bounds__(256) void norm_diag_kernel(
    const float* __restrict__ q, const float* __restrict__ k,
    ushort* __restrict__ qn, ushort* __restrict__ kn, float* __restrict__ diag) {
  const int wave = threadIdx.x >> 6;
  const int lane = threadIdx.x & 63;
  const int row = blockIdx.x * 4 + wave;          // one wave per row
  const float4* q4 = reinterpret_cast<const float4*>(q + (size_t)row * ND);
  const float4* k4 = reinterpret_cast<const float4*>(k + (size_t)row * ND);
  float4 qv = q4[lane];                            // 4 floats/lane * 64 = 256
  float4 kv = k4[lane];
  float sq = qv.x * qv.x + qv.y * qv.y + qv.z * qv.z + qv.w * qv.w;
  float sk = kv.x * kv.x + kv.y * kv.y + kv.z * kv.z + kv.w * kv.w;
  float dp = qv.x * kv.x + qv.y * kv.y + qv.z * kv.z + qv.w * kv.w;
#pragma unroll
  for (int m = 1; m < 64; m <<= 1) {
    sq += __shfl_xor(sq, m);
    sk += __shfl_xor(sk, m);
    dp += __shfl_xor(dp, m);
  }
  const float iq = 1.0f / fmaxf(sqrtf(sq), 1e-12f);   // F.normalize eps
  const float ik = 1.0f / fmaxf(sqrtf(sk), 1e-12f);
  union { ushort4 u; __hip_bfloat16 h[4]; } pq, pk;
  pq.h[0] = __float2bfloat16(qv.x * iq);
  pq.h[1] = __float2bfloat16(qv.y * iq);
  pq.h[2] = __float2bfloat16(qv.z * iq);
  pq.h[3] = __float2bfloat16(qv.w * iq);
  pk.h[0] = __float2bfloat16(kv.x * ik);
  pk.h[1] = __float2bfloat16(kv.y * ik);
  pk.h[2] = __float2bfloat16(kv.z * ik);
  pk.h[3] = __float2bfloat16(kv.w * ik);
  reinterpret_cast<ushort4*>(qn)[(size_t)row * (ND / 4) + lane] = pq.u;
  reinterpret_cast<ushort4*>(kn)[(size_t)row * (ND / 4) + lane] = pk.u;
  if (lane == 0) diag[row] = __expf(dp * iq * ik * TEMP_INV);  // exact fp32 diag
}

// ---------------- kernel 2: fused bf16 MFMA GEMM + exp + row/col reduce ------
#define BM 128
#define BN 128
#define BK 64
#define LDK 72   // +8 shorts pad: fragment-read stride 144B -> spreads banks

__global__ __launch_bounds__(256) void gemm_exp_reduce_kernel(
    const ushort* __restrict__ qn, const ushort* __restrict__ kn,
    float* __restrict__ rowsum, float* __restrict__ colsum) {
  __shared__ ushort As[BM][LDK];
  __shared__ ushort Bs[BN][LDK];
  const int tid  = threadIdx.x;
  const int lane = tid & 63;
  const int wave = tid >> 6;          // 4 waves: 2x2 of 64x64 sub-tiles
  const int wr = wave >> 1;
  const int wc = wave & 1;
  const int l15 = lane & 15;
  const int lhi = lane >> 4;
  const int brow = blockIdx.y * BM;
  const int bcol = blockIdx.x * BN;

  f32x4 acc[4][4];
#pragma unroll
  for (int mf = 0; mf < 4; ++mf)
#pragma unroll
    for (int nf = 0; nf < 4; ++nf)
      acc[mf][nf] = (f32x4){0.f, 0.f, 0.f, 0.f};

  for (int kt = 0; kt < ND; kt += BK) {
    // stage 128x64 shorts of each matrix; 1024 chunks of 8 shorts, 4/thread
#pragma unroll
    for (int i = 0; i < 4; ++i) {
      const int c  = tid + i * 256;       // 0..1023
      const int r  = c >> 3;              // 8 chunks per row
      const int kc = (c & 7) * 8;
      s16x8 va = *reinterpret_cast<const s16x8*>(&qn[(size_t)(brow + r) * ND + kt + kc]);
      s16x8 vb = *reinterpret_cast<const s16x8*>(&kn[(size_t)(bcol + r) * ND + kt + kc]);
      *reinterpret_cast<s16x8*>(&As[r][kc]) = va;
      *reinterpret_cast<s16x8*>(&Bs[r][kc]) = vb;
    }
    __syncthreads();
#pragma unroll
    for (int ks = 0; ks < 2; ++ks) {
      s16x8 af[4], bfrag[4];
#pragma unroll
      for (int mf = 0; mf < 4; ++mf)
        af[mf] = *reinterpret_cast<const s16x8*>(&As[wr * 64 + mf * 16 + l15][ks * 32 + lhi * 8]);
#pragma unroll
      for (int nf = 0; nf < 4; ++nf)
        bfrag[nf] = *reinterpret_cast<const s16x8*>(&Bs[wc * 64 + nf * 16 + l15][ks * 32 + lhi * 8]);
#pragma unroll
      for (int mf = 0; mf < 4; ++mf)
#pragma unroll
        for (int nf = 0; nf < 4; ++nf)
          acc[mf][nf] = __builtin_amdgcn_mfma_f32_16x16x32_bf16(
              af[mf], bfrag[nf], acc[mf][nf], 0, 0, 0);
    }
    __syncthreads();
  }

  // epilogue: E = exp(S / T), in-register
#pragma unroll
  for (int mf = 0; mf < 4; ++mf)
#pragma unroll
    for (int nf = 0; nf < 4; ++nf)
#pragma unroll
      for (int j = 0; j < 4; ++j)
        acc[mf][nf][j] = __expf(acc[mf][nf][j] * TEMP_INV);

  // C/D layout (m89-verified): col = lane&15, row = (lane>>4)*4 + j
  // row sums: sum over nf in-register, then over the 16 cols (lane bits 0-3)
#pragma unroll
  for (int mf = 0; mf < 4; ++mf) {
#pragma unroll
    for (int j = 0; j < 4; ++j) {
      float v = acc[mf][0][j] + acc[mf][1][j] + acc[mf][2][j] + acc[mf][3][j];
      v += __shfl_xor(v, 1);
      v += __shfl_xor(v, 2);
      v += __shfl_xor(v, 4);
      v += __shfl_xor(v, 8);
      if (l15 == 0) {
        const int row = brow + wr * 64 + mf * 16 + lhi * 4 + j;
        atomicAdd(&rowsum[row], v);
      }
    }
  }
  // col sums: sum over mf,j in-register, then over rows (lane bits 4-5)
#pragma unroll
  for (int nf = 0; nf < 4; ++nf) {
    float c = 0.f;
#pragma unroll
    for (int mf = 0; mf < 4; ++mf)
#pragma unroll
      for (int j = 0; j < 4; ++j)
        c += acc[mf][nf][j];
    c += __shfl_xor(c, 16);
    c += __shfl_xor(c, 32);
    if (lhi == 0) {
      const int col = bcol + wc * 64 + nf * 16 + l15;
      atomicAdd(&colsum[col], c);
    }
  }
}

// ---------------- kernel 3: final scalar loss --------------------------------
__global__ __launch_bounds__(256) void loss_kernel(
    const float* __restrict__ diag, const float* __restrict__ rowsum,
    const float* __restrict__ colsum, float* __restrict__ out) {
  float acc = 0.f;
  for (int i = threadIdx.x; i < NB; i += 256) {
    const float d = diag[i];
    acc -= __logf(d / rowsum[i] + EPS);
    acc -= __logf(d / colsum[i] + EPS);
  }
#pragma unroll
  for (int m = 1; m < 64; m <<= 1) acc += __shfl_xor(acc, m);
  __shared__ float ls[4];
  const int wave = threadIdx.x >> 6;
  if ((threadIdx.x & 63) == 0) ls[wave] = acc;
  __syncthreads();
  if (threadIdx.x == 0)
    out[0] = (ls[0] + ls[1] + ls[2] + ls[3]) * (1.0f / NB);
}

extern "C" void kernel_launch(void* const* d_in, const int* in_sizes, int n_in,
                              void* d_out, int out_size, void* d_ws, size_t ws_size,
                              hipStream_t stream) {
  const float* q = (const float*)d_in[0];
  const float* k = (const float*)d_in[1];
  char* ws = (char*)d_ws;
  ushort* qn   = (ushort*)ws;                                   // 4 MB
  ushort* kn   = (ushort*)(ws + (size_t)NB * ND * 2);           // 4 MB
  float*  diag = (float*)(ws + (size_t)NB * ND * 4);            // 32 KB
  float*  rowsum = diag + NB;                                   // 32 KB
  float*  colsum = rowsum + NB;                                 // 32 KB
  float*  out = (float*)d_out;

  hipMemsetAsync(rowsum, 0, 2 * NB * sizeof(float), stream);    // row+col accums

  norm_diag_kernel<<<NB / 4, 256, 0, stream>>>(q, k, qn, kn, diag);
  gemm_exp_reduce_kernel<<<dim3(NB / BN, NB / BM), 256, 0, stream>>>(
      qn, kn, rowsum, colsum);
  loss_kernel<<<1, 256, 0, stream>>>(diag, rowsum, colsum, out);
}